// Round 8
// baseline (110.864 us; speedup 1.0000x reference)
//
#include <hip/hip_runtime.h>

// AdderNet CNN, fused 3-kernel pipeline:
//   K1 conv1+pool4 (+BN1 partials)  -> K2 conv2+pool2 (+BN2 partials, BN1 applied on load)
//   -> K3 fc + BN3 in a single block (BN2 applied on load, wfc in LDS).
// Max-pool over raw conv outputs commutes with the positive-scale BN affine, so pools
// run on raw values and the affine+ReLU folds into the consumer's load path.
// BN stats use deterministic two-level reductions (per-block partials, no atomics).
//
// ws layout: doubles p1[2][5][128] (conv1 sum/sumsq partials, [co][b*2+t]),
//            p2[2][10][64] (conv2 partials, [co][b]) = 20480 B total;
// floats after: Bv raw-pooled1 [64][5][122][2] (78080), Draw raw-pooled2 [64][590] (37760)

#define BN_EPS 1e-5f

// K1: conv1 + maxpool4x4 (raw) + BN1 partials. grid 640 = (b*5+co)*2+t ; block 256.
// Thread = one of 244 output rows: 8 cols x 60 L1 terms in regs; pool via 4-lane shfl.
__global__ __launch_bounds__(256) void conv1p1_kernel(
    const float* __restrict__ in, const float* __restrict__ w1,
    float* __restrict__ Bo, double* __restrict__ p1)
{
    int bid = blockIdx.x;
    int t  = bid & 1;
    int bc = bid >> 1;
    int co = bc % 5;
    int b  = bc / 5;
    int tid = threadIdx.x;

    // stage input rows [t*244, t*244+255) : 255 rows x 12 = 3060 floats
    __shared__ float img[255 * 12 + 4];
    const float4* ip4 = (const float4*)(in + b * 5988 + t * 2928);
    float4* img4 = (float4*)img;
    for (int i = tid; i < 765; i += 256) img4[i] = ip4[i];

    float w[60];
    #pragma unroll
    for (int i = 0; i < 60; i++) w[i] = w1[co * 60 + i];
    __syncthreads();

    float ls = 0.f, lss = 0.f;
    float m0 = 0.f, m1 = 0.f;
    if (tid < 244) {
        int y = tid;
        float s[8] = {0.f,0.f,0.f,0.f,0.f,0.f,0.f,0.f};
        #pragma unroll
        for (int kh = 0; kh < 12; kh++) {
            const float* rp = &img[(y + kh) * 12];
            float4 r0 = *(const float4*)(rp);
            float4 r1 = *(const float4*)(rp + 4);
            float4 r2 = *(const float4*)(rp + 8);
            float row[12] = {r0.x,r0.y,r0.z,r0.w, r1.x,r1.y,r1.z,r1.w, r2.x,r2.y,r2.z,r2.w};
            #pragma unroll
            for (int x = 0; x < 8; x++) {
                #pragma unroll
                for (int kw = 0; kw < 5; kw++)
                    s[x] += fabsf(row[x + kw] - w[kh * 5 + kw]);
            }
        }
        float o[8];
        #pragma unroll
        for (int x = 0; x < 8; x++) { o[x] = -s[x]; ls += o[x]; lss += o[x] * o[x]; }
        m0 = fmaxf(fmaxf(o[0], o[1]), fmaxf(o[2], o[3]));
        m1 = fmaxf(fmaxf(o[4], o[5]), fmaxf(o[6], o[7]));
    }
    // 4-row pool reduction within the wave (windows lanes 4q..4q+3; 244 = 61*4 aligned)
    m0 = fmaxf(m0, __shfl_down(m0, 1, 64));
    m0 = fmaxf(m0, __shfl_down(m0, 2, 64));
    m1 = fmaxf(m1, __shfl_down(m1, 1, 64));
    m1 = fmaxf(m1, __shfl_down(m1, 2, 64));
    if (tid < 244 && (tid & 3) == 0) {
        int p = t * 61 + (tid >> 2);
        float* bp = Bo + ((size_t)(b * 5 + co) * 122 + p) * 2;
        bp[0] = m0; bp[1] = m1;
    }

    __shared__ double rs[256], rss[256];
    rs[tid] = (double)ls; rss[tid] = (double)lss;
    __syncthreads();
    for (int ofs = 128; ofs > 0; ofs >>= 1) {
        if (tid < ofs) { rs[tid] += rs[tid + ofs]; rss[tid] += rss[tid + ofs]; }
        __syncthreads();
    }
    if (tid == 0) {
        p1[co * 128 + b * 2 + t]       = rs[0];
        p1[640 + co * 128 + b * 2 + t] = rss[0];
    }
}

// K2: conv2 + maxpool2x2 (raw) + BN2 partials. BN1 (from p1) applied on stage-in.
// grid 640 = b*10+co ; block 64 (1 wave). Thread = pooled row (59 active).
__global__ __launch_bounds__(64) void conv2p2_kernel(
    const float* __restrict__ Bi, const double* __restrict__ p1,
    double* __restrict__ p2,
    const float* __restrict__ g1, const float* __restrict__ b1,
    const float* __restrict__ w2,
    float* __restrict__ Draw)
{
    int bid = blockIdx.x;
    int co = bid % 10;
    int b  = bid / 10;
    int tid = threadIdx.x;   // = lane

    // BN1 scale/shift per input channel: reduce p1[co][0..127] in-wave, broadcast.
    float sc1[5], sh1[5];
    const double N1 = 64.0 * 488.0 * 8.0;
    #pragma unroll
    for (int c = 0; c < 5; c++) {
        double s = p1[c * 128 + tid] + p1[c * 128 + 64 + tid];
        double q = p1[640 + c * 128 + tid] + p1[640 + c * 128 + 64 + tid];
        #pragma unroll
        for (int ofs = 32; ofs > 0; ofs >>= 1) {
            s += __shfl_down(s, ofs, 64);
            q += __shfl_down(q, ofs, 64);
        }
        s = __shfl(s, 0, 64);
        q = __shfl(q, 0, 64);
        double m = s / N1;
        double v = q / N1 - m * m;
        sc1[c] = g1[c] * rsqrtf((float)v + BN_EPS);
        sh1[c] = b1[c] - (float)m * sc1[c];
    }

    __shared__ float img[5 * 122 * 2];   // post BN1+ReLU
    const float4* bp4 = (const float4*)(Bi + (size_t)b * 1220);
    float4* img4 = (float4*)img;
    for (int i = tid; i < 305; i += 64) {
        int c = i / 61;                  // 61 float4 per channel (244 floats)
        float4 r = bp4[i];
        r.x = fmaxf(0.f, r.x * sc1[c] + sh1[c]);
        r.y = fmaxf(0.f, r.y * sc1[c] + sh1[c]);
        r.z = fmaxf(0.f, r.z * sc1[c] + sh1[c]);
        r.w = fmaxf(0.f, r.w * sc1[c] + sh1[c]);
        img4[i] = r;
    }

    float w[25];
    #pragma unroll
    for (int i = 0; i < 25; i++) w[i] = w2[co * 25 + i];
    __syncthreads();

    float ls = 0.f, lss = 0.f;
    if (tid < 59) {
        const float2* img2 = (const float2*)img;
        float o[4];
        #pragma unroll
        for (int r = 0; r < 2; r++) {
            int row = 2 * tid + r;
            float s0 = 0.f, s1 = 0.f;
            #pragma unroll
            for (int cin = 0; cin < 5; cin++)
                #pragma unroll
                for (int kh = 0; kh < 5; kh++) {
                    float2 f = img2[cin * 122 + row + kh];
                    float wv = w[cin * 5 + kh];
                    s0 += fabsf(f.x - wv);
                    s1 += fabsf(f.y - wv);
                }
            o[r * 2]     = -s0;
            o[r * 2 + 1] = -s1;
        }
        #pragma unroll
        for (int i = 0; i < 4; i++) { ls += o[i]; lss += o[i] * o[i]; }
        Draw[(size_t)(b * 10 + co) * 59 + tid] =
            fmaxf(fmaxf(o[0], o[1]), fmaxf(o[2], o[3]));
    }

    double dls = (double)ls, dlss = (double)lss;
    #pragma unroll
    for (int ofs = 32; ofs > 0; ofs >>= 1) {
        dls  += __shfl_down(dls, ofs, 64);
        dlss += __shfl_down(dlss, ofs, 64);
    }
    if (tid == 0) {
        p2[co * 64 + b]       = dls;
        p2[640 + co * 64 + b] = dlss;
    }
}

// K3: FC adder (BN2 applied on load) + BN3, single block of 1024 threads.
// wfc staged in LDS; wave w handles batch rows b = 4w..4w+3 with x in registers;
// E kept in LDS; BN3 stats via double wave-reductions.
__global__ __launch_bounds__(1024) void fcbn3_kernel(
    const float* __restrict__ Draw, const double* __restrict__ p2,
    const float* __restrict__ g2, const float* __restrict__ b2,
    const float* __restrict__ wfc,
    const float* __restrict__ g3, const float* __restrict__ b3,
    float* __restrict__ out)
{
    int tid  = threadIdx.x;
    int w    = tid >> 6;
    int lane = tid & 63;

    __shared__ float wsm[5900];
    __shared__ float E_lds[640];
    __shared__ float sc2s[10], sh2s[10], sc3s[10], sh3s[10];

    const float4* wf4 = (const float4*)wfc;
    float4* wsm4 = (float4*)wsm;
    for (int i = tid; i < 1475; i += 1024) wsm4[i] = wf4[i];

    // BN2 scale/shift: wave w<10 reduces p2[w][0..63]
    if (w < 10) {
        const double N2 = 64.0 * 118.0 * 2.0;
        double s = p2[w * 64 + lane];
        double q = p2[640 + w * 64 + lane];
        #pragma unroll
        for (int ofs = 32; ofs > 0; ofs >>= 1) {
            s += __shfl_down(s, ofs, 64);
            q += __shfl_down(q, ofs, 64);
        }
        if (lane == 0) {
            double m = s / N2;
            double v = q / N2 - m * m;
            float sc = g2[w] * rsqrtf((float)v + BN_EPS);
            sc2s[w] = sc;
            sh2s[w] = b2[w] - (float)m * sc;
        }
    }
    __syncthreads();

    // FC: wave w -> batch rows 4w..4w+3; lane covers k = it*64+lane
    for (int i = 0; i < 4; i++) {
        int b = w * 4 + i;
        float x[10];
        #pragma unroll
        for (int it = 0; it < 10; it++) {
            int k = it * 64 + lane;
            float xv = 0.f;
            if (k < 590) {
                int c = k / 59;
                xv = fmaxf(0.f, Draw[b * 590 + k] * sc2s[c] + sh2s[c]);
            }
            x[it] = xv;
        }
        for (int co = 0; co < 10; co++) {
            float s = 0.f;
            #pragma unroll
            for (int it = 0; it < 10; it++) {
                int k = it * 64 + lane;
                if (k < 590) s += fabsf(x[it] - wsm[co * 590 + k]);
            }
            #pragma unroll
            for (int ofs = 32; ofs > 0; ofs >>= 1) s += __shfl_down(s, ofs, 64);
            if (lane == 0) E_lds[b * 10 + co] = -s;
        }
    }
    __syncthreads();

    // BN3 stats: wave w<10 reduces channel w over 64 batch entries
    if (w < 10) {
        float e = E_lds[lane * 10 + w];
        double s = (double)e, q = (double)e * (double)e;
        #pragma unroll
        for (int ofs = 32; ofs > 0; ofs >>= 1) {
            s += __shfl_down(s, ofs, 64);
            q += __shfl_down(q, ofs, 64);
        }
        if (lane == 0) {
            double m = s / 64.0;
            double v = q / 64.0 - m * m;
            float sc = g3[w] * rsqrtf((float)v + BN_EPS);
            sc3s[w] = sc;
            sh3s[w] = b3[w] - (float)m * sc;
        }
    }
    __syncthreads();

    if (tid < 640) {
        int co = tid % 10;
        out[tid] = E_lds[tid] * sc3s[co] + sh3s[co];
    }
}

extern "C" void kernel_launch(void* const* d_in, const int* in_sizes, int n_in,
                              void* d_out, int out_size, void* d_ws, size_t ws_size,
                              hipStream_t stream) {
    const float* in  = (const float*)d_in[0];
    const float* w1  = (const float*)d_in[1];
    const float* g1  = (const float*)d_in[2];
    const float* b1  = (const float*)d_in[3];
    const float* w2  = (const float*)d_in[4];
    const float* g2  = (const float*)d_in[5];
    const float* b2  = (const float*)d_in[6];
    const float* wfc = (const float*)d_in[7];
    const float* g3  = (const float*)d_in[8];
    const float* b3  = (const float*)d_in[9];
    float* out = (float*)d_out;

    double* p1 = (double*)d_ws;                  // [2][5][128]  = 1280 doubles
    double* p2 = p1 + 1280;                      // [2][10][64]  = 1280 doubles
    float* Bv   = (float*)((char*)d_ws + 20480); // raw pooled1, 78080 floats
    float* Draw = Bv + 78080;                    // raw pooled2, 37760 floats

    conv1p1_kernel<<<640, 256, 0, stream>>>(in, w1, Bv, p1);
    conv2p2_kernel<<<640, 64, 0, stream>>>(Bv, p1, p2, g1, b1, w2, Draw);
    fcbn3_kernel<<<1, 1024, 0, stream>>>(Draw, p2, g2, b2, wfc, g3, b3, out);
}

// Round 9
// 98.128 us; speedup vs baseline: 1.1298x; 1.1298x over previous
//
#include <hip/hip_runtime.h>

// AdderNet CNN, fused 3-kernel pipeline:
//   K1 conv1+pool4 (+BN1 partials, zeroes fc-counter)
//   K2 conv2+pool2 (+BN2 partials, BN1 applied on load)
//   K3 fc (160 blocks, BN2 applied on load) + BN3 via last-block-finalizes.
// Max-pool over raw conv outputs commutes with the positive-scale BN affine, so pools
// run on raw values and the affine+ReLU folds into the consumer's load path.
// BN stats use deterministic two-level reductions (per-block partials, no atomics on stats).
//
// ws layout: doubles p1[2][5][128], p2[2][10][64] (20480 B);
// floats Bv raw-pooled1 (78080), Draw raw-pooled2 (37760), E (640); then u32 counter.

#define BN_EPS 1e-5f

// K1: conv1 + maxpool4x4 (raw) + BN1 partials. grid 640 = (b*5+co)*2+t ; block 256.
// Thread = one of 244 output rows: 8 cols x 60 L1 terms in regs; pool via 4-lane shfl.
__global__ __launch_bounds__(256) void conv1p1_kernel(
    const float* __restrict__ in, const float* __restrict__ w1,
    float* __restrict__ Bo, double* __restrict__ p1,
    unsigned int* __restrict__ counter)
{
    int bid = blockIdx.x;
    if (bid == 0 && threadIdx.x == 0) *counter = 0;   // for K3's last-block detect
    int t  = bid & 1;
    int bc = bid >> 1;
    int co = bc % 5;
    int b  = bc / 5;
    int tid = threadIdx.x;

    // stage input rows [t*244, t*244+255) : 255 rows x 12 = 3060 floats
    __shared__ float img[255 * 12 + 4];
    const float4* ip4 = (const float4*)(in + b * 5988 + t * 2928);
    float4* img4 = (float4*)img;
    for (int i = tid; i < 765; i += 256) img4[i] = ip4[i];

    float w[60];
    #pragma unroll
    for (int i = 0; i < 60; i++) w[i] = w1[co * 60 + i];
    __syncthreads();

    float ls = 0.f, lss = 0.f;
    float m0 = 0.f, m1 = 0.f;
    if (tid < 244) {
        int y = tid;
        float s[8] = {0.f,0.f,0.f,0.f,0.f,0.f,0.f,0.f};
        #pragma unroll
        for (int kh = 0; kh < 12; kh++) {
            const float* rp = &img[(y + kh) * 12];
            float4 r0 = *(const float4*)(rp);
            float4 r1 = *(const float4*)(rp + 4);
            float4 r2 = *(const float4*)(rp + 8);
            float row[12] = {r0.x,r0.y,r0.z,r0.w, r1.x,r1.y,r1.z,r1.w, r2.x,r2.y,r2.z,r2.w};
            #pragma unroll
            for (int x = 0; x < 8; x++) {
                #pragma unroll
                for (int kw = 0; kw < 5; kw++)
                    s[x] += fabsf(row[x + kw] - w[kh * 5 + kw]);
            }
        }
        float o[8];
        #pragma unroll
        for (int x = 0; x < 8; x++) { o[x] = -s[x]; ls += o[x]; lss += o[x] * o[x]; }
        m0 = fmaxf(fmaxf(o[0], o[1]), fmaxf(o[2], o[3]));
        m1 = fmaxf(fmaxf(o[4], o[5]), fmaxf(o[6], o[7]));
    }
    // 4-row pool reduction within the wave (windows lanes 4q..4q+3; 244 = 61*4 aligned)
    m0 = fmaxf(m0, __shfl_down(m0, 1, 64));
    m0 = fmaxf(m0, __shfl_down(m0, 2, 64));
    m1 = fmaxf(m1, __shfl_down(m1, 1, 64));
    m1 = fmaxf(m1, __shfl_down(m1, 2, 64));
    if (tid < 244 && (tid & 3) == 0) {
        int p = t * 61 + (tid >> 2);
        float* bp = Bo + ((size_t)(b * 5 + co) * 122 + p) * 2;
        bp[0] = m0; bp[1] = m1;
    }

    __shared__ double rs[256], rss[256];
    rs[tid] = (double)ls; rss[tid] = (double)lss;
    __syncthreads();
    for (int ofs = 128; ofs > 0; ofs >>= 1) {
        if (tid < ofs) { rs[tid] += rs[tid + ofs]; rss[tid] += rss[tid + ofs]; }
        __syncthreads();
    }
    if (tid == 0) {
        p1[co * 128 + b * 2 + t]       = rs[0];
        p1[640 + co * 128 + b * 2 + t] = rss[0];
    }
}

// K2: conv2 + maxpool2x2 (raw) + BN2 partials. BN1 (from p1) applied on stage-in.
// grid 640 = b*10+co ; block 64 (1 wave). Thread = pooled row (59 active).
__global__ __launch_bounds__(64) void conv2p2_kernel(
    const float* __restrict__ Bi, const double* __restrict__ p1,
    double* __restrict__ p2,
    const float* __restrict__ g1, const float* __restrict__ b1,
    const float* __restrict__ w2,
    float* __restrict__ Draw)
{
    int bid = blockIdx.x;
    int co = bid % 10;
    int b  = bid / 10;
    int tid = threadIdx.x;   // = lane

    // BN1 scale/shift per input channel: reduce p1[co][0..127] in-wave, broadcast.
    float sc1[5], sh1[5];
    const double N1 = 64.0 * 488.0 * 8.0;
    #pragma unroll
    for (int c = 0; c < 5; c++) {
        double s = p1[c * 128 + tid] + p1[c * 128 + 64 + tid];
        double q = p1[640 + c * 128 + tid] + p1[640 + c * 128 + 64 + tid];
        #pragma unroll
        for (int ofs = 32; ofs > 0; ofs >>= 1) {
            s += __shfl_down(s, ofs, 64);
            q += __shfl_down(q, ofs, 64);
        }
        s = __shfl(s, 0, 64);
        q = __shfl(q, 0, 64);
        double m = s / N1;
        double v = q / N1 - m * m;
        sc1[c] = g1[c] * rsqrtf((float)v + BN_EPS);
        sh1[c] = b1[c] - (float)m * sc1[c];
    }

    __shared__ float img[5 * 122 * 2];   // post BN1+ReLU
    const float4* bp4 = (const float4*)(Bi + (size_t)b * 1220);
    float4* img4 = (float4*)img;
    for (int i = tid; i < 305; i += 64) {
        int c = i / 61;                  // 61 float4 per channel (244 floats)
        float4 r = bp4[i];
        r.x = fmaxf(0.f, r.x * sc1[c] + sh1[c]);
        r.y = fmaxf(0.f, r.y * sc1[c] + sh1[c]);
        r.z = fmaxf(0.f, r.z * sc1[c] + sh1[c]);
        r.w = fmaxf(0.f, r.w * sc1[c] + sh1[c]);
        img4[i] = r;
    }

    float w[25];
    #pragma unroll
    for (int i = 0; i < 25; i++) w[i] = w2[co * 25 + i];
    __syncthreads();

    float ls = 0.f, lss = 0.f;
    if (tid < 59) {
        const float2* img2 = (const float2*)img;
        float o[4];
        #pragma unroll
        for (int r = 0; r < 2; r++) {
            int row = 2 * tid + r;
            float s0 = 0.f, s1 = 0.f;
            #pragma unroll
            for (int cin = 0; cin < 5; cin++)
                #pragma unroll
                for (int kh = 0; kh < 5; kh++) {
                    float2 f = img2[cin * 122 + row + kh];
                    float wv = w[cin * 5 + kh];
                    s0 += fabsf(f.x - wv);
                    s1 += fabsf(f.y - wv);
                }
            o[r * 2]     = -s0;
            o[r * 2 + 1] = -s1;
        }
        #pragma unroll
        for (int i = 0; i < 4; i++) { ls += o[i]; lss += o[i] * o[i]; }
        Draw[(size_t)(b * 10 + co) * 59 + tid] =
            fmaxf(fmaxf(o[0], o[1]), fmaxf(o[2], o[3]));
    }

    double dls = (double)ls, dlss = (double)lss;
    #pragma unroll
    for (int ofs = 32; ofs > 0; ofs >>= 1) {
        dls  += __shfl_down(dls, ofs, 64);
        dlss += __shfl_down(dlss, ofs, 64);
    }
    if (tid == 0) {
        p2[co * 64 + b]       = dls;
        p2[640 + co * 64 + b] = dlss;
    }
}

// K3: FC adder (BN2 applied on load), 160 blocks x 256; wave = one (b,co) pair.
// BN3 fused via last-block-finalizes: E written with device-scope atomicExch,
// block counter via atomicAdd; the 160th block stages E, computes BN3, writes out.
__global__ __launch_bounds__(256) void fc_bn3_kernel(
    const float* __restrict__ Draw, const double* __restrict__ p2,
    const float* __restrict__ g2, const float* __restrict__ b2,
    const float* __restrict__ wfc,
    const float* __restrict__ g3, const float* __restrict__ b3,
    float* __restrict__ E, unsigned int* __restrict__ counter,
    float* __restrict__ out)
{
    int tid = threadIdx.x;

    __shared__ float sc2s[10], sh2s[10];
    if (tid < 10) {
        const double N2 = 64.0 * 118.0 * 2.0;
        double s = 0.0, q = 0.0;
        for (int bb = 0; bb < 64; bb++) {
            s += p2[tid * 64 + bb];
            q += p2[640 + tid * 64 + bb];
        }
        double m = s / N2;
        double v = q / N2 - m * m;
        float sc = g2[tid] * rsqrtf((float)v + BN_EPS);
        sc2s[tid] = sc;
        sh2s[tid] = b2[tid] - (float)m * sc;
    }
    __syncthreads();

    int pair = blockIdx.x * 4 + (tid >> 6);
    int lane = tid & 63;
    int b = pair / 10, co = pair % 10;
    const float* dp = Draw + (size_t)b * 590;
    const float* wp = wfc + (size_t)co * 590;
    float s = 0.f;
    #pragma unroll
    for (int j = 0; j < 10; j++) {
        int k = lane + j * 64;
        if (k < 590) {
            int c = k / 59;
            float x = fmaxf(0.f, dp[k] * sc2s[c] + sh2s[c]);
            s += fabsf(x - wp[k]);
        }
    }
    #pragma unroll
    for (int ofs = 32; ofs > 0; ofs >>= 1) s += __shfl_down(s, ofs, 64);
    if (lane == 0) atomicExch(&E[pair], -s);   // device-scope publish

    // ---- last-block BN3 ----
    __shared__ unsigned int lastflag;
    __syncthreads();                            // all 4 waves' E published
    if (tid == 0) {
        __threadfence();
        lastflag = (atomicAdd(counter, 1u) == 159u) ? 1u : 0u;
    }
    __syncthreads();
    if (lastflag) {
        __threadfence();                        // acquire before reading E
        __shared__ float E_lds[640];
        __shared__ float sc3s[10], sh3s[10];
        for (int i = tid; i < 640; i += 256) E_lds[i] = E[i];
        __syncthreads();
        if (tid < 10) {
            double sm = 0.0, ss = 0.0;
            for (int bb = 0; bb < 64; bb++) {
                double v = (double)E_lds[bb * 10 + tid];
                sm += v; ss += v * v;
            }
            double m = sm / 64.0;
            double v = ss / 64.0 - m * m;
            float sc = g3[tid] * rsqrtf((float)v + BN_EPS);
            sc3s[tid] = sc;
            sh3s[tid] = b3[tid] - (float)m * sc;
        }
        __syncthreads();
        for (int i = tid; i < 640; i += 256) {
            int c = i % 10;
            out[i] = E_lds[i] * sc3s[c] + sh3s[c];
        }
    }
}

extern "C" void kernel_launch(void* const* d_in, const int* in_sizes, int n_in,
                              void* d_out, int out_size, void* d_ws, size_t ws_size,
                              hipStream_t stream) {
    const float* in  = (const float*)d_in[0];
    const float* w1  = (const float*)d_in[1];
    const float* g1  = (const float*)d_in[2];
    const float* b1  = (const float*)d_in[3];
    const float* w2  = (const float*)d_in[4];
    const float* g2  = (const float*)d_in[5];
    const float* b2  = (const float*)d_in[6];
    const float* wfc = (const float*)d_in[7];
    const float* g3  = (const float*)d_in[8];
    const float* b3  = (const float*)d_in[9];
    float* out = (float*)d_out;

    double* p1 = (double*)d_ws;                  // [2][5][128]  = 1280 doubles
    double* p2 = p1 + 1280;                      // [2][10][64]  = 1280 doubles
    float* Bv   = (float*)((char*)d_ws + 20480); // raw pooled1, 78080 floats
    float* Draw = Bv + 78080;                    // raw pooled2, 37760 floats
    float* Ev   = Draw + 37760;                  // fc out, 640 floats
    unsigned int* counter = (unsigned int*)(Ev + 640);

    conv1p1_kernel<<<640, 256, 0, stream>>>(in, w1, Bv, p1, counter);
    conv2p2_kernel<<<640, 64, 0, stream>>>(Bv, p1, p2, g1, b1, w2, Draw);
    fc_bn3_kernel<<<160, 256, 0, stream>>>(Draw, p2, g2, b2, wfc, g3, b3,
                                           Ev, counter, out);
}

// Round 12
// 97.851 us; speedup vs baseline: 1.1330x; 1.0028x over previous
//
#include <hip/hip_runtime.h>

// AdderNet CNN, fused 3-kernel pipeline (proven R9 configuration, 98.1 us):
//   K1 conv1+pool4 (+BN1 partials, zeroes fc-counter)
//   K2 conv2+pool2 (+BN2 partials, BN1 applied on load)
//   K3 fc (160 blocks, BN2 applied on load) + BN3 via last-block-finalizes.
// Max-pool over raw conv outputs commutes with the positive-scale BN affine, so pools
// run on raw values and the affine+ReLU folds into the consumer's load path.
// BN stats use deterministic two-level reductions (per-block partials, no atomics on stats).
//
// Cooperative single-kernel variant was tried twice (R10/R11) and fails on this
// harness (hipLaunchCooperativeKernel incompatible with graph capture) — do not retry.
//
// ws layout: doubles p1[2][5][128], p2[2][10][64] (20480 B);
// floats Bv raw-pooled1 (78080), Draw raw-pooled2 (37760), E (640); then u32 counter.

#define BN_EPS 1e-5f

// K1: conv1 + maxpool4x4 (raw) + BN1 partials. grid 640 = (b*5+co)*2+t ; block 256.
// Thread = one of 244 output rows: 8 cols x 60 L1 terms in regs; pool via 4-lane shfl.
__global__ __launch_bounds__(256) void conv1p1_kernel(
    const float* __restrict__ in, const float* __restrict__ w1,
    float* __restrict__ Bo, double* __restrict__ p1,
    unsigned int* __restrict__ counter)
{
    int bid = blockIdx.x;
    if (bid == 0 && threadIdx.x == 0) *counter = 0;   // for K3's last-block detect
    int t  = bid & 1;
    int bc = bid >> 1;
    int co = bc % 5;
    int b  = bc / 5;
    int tid = threadIdx.x;

    // stage input rows [t*244, t*244+255) : 255 rows x 12 = 3060 floats
    __shared__ float img[255 * 12 + 4];
    const float4* ip4 = (const float4*)(in + b * 5988 + t * 2928);
    float4* img4 = (float4*)img;
    for (int i = tid; i < 765; i += 256) img4[i] = ip4[i];

    float w[60];
    #pragma unroll
    for (int i = 0; i < 60; i++) w[i] = w1[co * 60 + i];
    __syncthreads();

    float ls = 0.f, lss = 0.f;
    float m0 = 0.f, m1 = 0.f;
    if (tid < 244) {
        int y = tid;
        float s[8] = {0.f,0.f,0.f,0.f,0.f,0.f,0.f,0.f};
        #pragma unroll
        for (int kh = 0; kh < 12; kh++) {
            const float* rp = &img[(y + kh) * 12];
            float4 r0 = *(const float4*)(rp);
            float4 r1 = *(const float4*)(rp + 4);
            float4 r2 = *(const float4*)(rp + 8);
            float row[12] = {r0.x,r0.y,r0.z,r0.w, r1.x,r1.y,r1.z,r1.w, r2.x,r2.y,r2.z,r2.w};
            #pragma unroll
            for (int x = 0; x < 8; x++) {
                #pragma unroll
                for (int kw = 0; kw < 5; kw++)
                    s[x] += fabsf(row[x + kw] - w[kh * 5 + kw]);
            }
        }
        float o[8];
        #pragma unroll
        for (int x = 0; x < 8; x++) { o[x] = -s[x]; ls += o[x]; lss += o[x] * o[x]; }
        m0 = fmaxf(fmaxf(o[0], o[1]), fmaxf(o[2], o[3]));
        m1 = fmaxf(fmaxf(o[4], o[5]), fmaxf(o[6], o[7]));
    }
    // 4-row pool reduction within the wave (windows lanes 4q..4q+3; 244 = 61*4 aligned)
    m0 = fmaxf(m0, __shfl_down(m0, 1, 64));
    m0 = fmaxf(m0, __shfl_down(m0, 2, 64));
    m1 = fmaxf(m1, __shfl_down(m1, 1, 64));
    m1 = fmaxf(m1, __shfl_down(m1, 2, 64));
    if (tid < 244 && (tid & 3) == 0) {
        int p = t * 61 + (tid >> 2);
        float* bp = Bo + ((size_t)(b * 5 + co) * 122 + p) * 2;
        bp[0] = m0; bp[1] = m1;
    }

    __shared__ double rs[256], rss[256];
    rs[tid] = (double)ls; rss[tid] = (double)lss;
    __syncthreads();
    for (int ofs = 128; ofs > 0; ofs >>= 1) {
        if (tid < ofs) { rs[tid] += rs[tid + ofs]; rss[tid] += rss[tid + ofs]; }
        __syncthreads();
    }
    if (tid == 0) {
        p1[co * 128 + b * 2 + t]       = rs[0];
        p1[640 + co * 128 + b * 2 + t] = rss[0];
    }
}

// K2: conv2 + maxpool2x2 (raw) + BN2 partials. BN1 (from p1) applied on stage-in.
// grid 640 = b*10+co ; block 64 (1 wave). Thread = pooled row (59 active).
__global__ __launch_bounds__(64) void conv2p2_kernel(
    const float* __restrict__ Bi, const double* __restrict__ p1,
    double* __restrict__ p2,
    const float* __restrict__ g1, const float* __restrict__ b1,
    const float* __restrict__ w2,
    float* __restrict__ Draw)
{
    int bid = blockIdx.x;
    int co = bid % 10;
    int b  = bid / 10;
    int tid = threadIdx.x;   // = lane

    // BN1 scale/shift per input channel: reduce p1[co][0..127] in-wave, broadcast.
    float sc1[5], sh1[5];
    const double N1 = 64.0 * 488.0 * 8.0;
    #pragma unroll
    for (int c = 0; c < 5; c++) {
        double s = p1[c * 128 + tid] + p1[c * 128 + 64 + tid];
        double q = p1[640 + c * 128 + tid] + p1[640 + c * 128 + 64 + tid];
        #pragma unroll
        for (int ofs = 32; ofs > 0; ofs >>= 1) {
            s += __shfl_down(s, ofs, 64);
            q += __shfl_down(q, ofs, 64);
        }
        s = __shfl(s, 0, 64);
        q = __shfl(q, 0, 64);
        double m = s / N1;
        double v = q / N1 - m * m;
        sc1[c] = g1[c] * rsqrtf((float)v + BN_EPS);
        sh1[c] = b1[c] - (float)m * sc1[c];
    }

    __shared__ float img[5 * 122 * 2];   // post BN1+ReLU
    const float4* bp4 = (const float4*)(Bi + (size_t)b * 1220);
    float4* img4 = (float4*)img;
    for (int i = tid; i < 305; i += 64) {
        int c = i / 61;                  // 61 float4 per channel (244 floats)
        float4 r = bp4[i];
        r.x = fmaxf(0.f, r.x * sc1[c] + sh1[c]);
        r.y = fmaxf(0.f, r.y * sc1[c] + sh1[c]);
        r.z = fmaxf(0.f, r.z * sc1[c] + sh1[c]);
        r.w = fmaxf(0.f, r.w * sc1[c] + sh1[c]);
        img4[i] = r;
    }

    float w[25];
    #pragma unroll
    for (int i = 0; i < 25; i++) w[i] = w2[co * 25 + i];
    __syncthreads();

    float ls = 0.f, lss = 0.f;
    if (tid < 59) {
        const float2* img2 = (const float2*)img;
        float o[4];
        #pragma unroll
        for (int r = 0; r < 2; r++) {
            int row = 2 * tid + r;
            float s0 = 0.f, s1 = 0.f;
            #pragma unroll
            for (int cin = 0; cin < 5; cin++)
                #pragma unroll
                for (int kh = 0; kh < 5; kh++) {
                    float2 f = img2[cin * 122 + row + kh];
                    float wv = w[cin * 5 + kh];
                    s0 += fabsf(f.x - wv);
                    s1 += fabsf(f.y - wv);
                }
            o[r * 2]     = -s0;
            o[r * 2 + 1] = -s1;
        }
        #pragma unroll
        for (int i = 0; i < 4; i++) { ls += o[i]; lss += o[i] * o[i]; }
        Draw[(size_t)(b * 10 + co) * 59 + tid] =
            fmaxf(fmaxf(o[0], o[1]), fmaxf(o[2], o[3]));
    }

    double dls = (double)ls, dlss = (double)lss;
    #pragma unroll
    for (int ofs = 32; ofs > 0; ofs >>= 1) {
        dls  += __shfl_down(dls, ofs, 64);
        dlss += __shfl_down(dlss, ofs, 64);
    }
    if (tid == 0) {
        p2[co * 64 + b]       = dls;
        p2[640 + co * 64 + b] = dlss;
    }
}

// K3: FC adder (BN2 applied on load), 160 blocks x 256; wave = one (b,co) pair.
// BN3 fused via last-block-finalizes: E written with device-scope atomicExch,
// block counter via atomicAdd; the 160th block stages E, computes BN3, writes out.
__global__ __launch_bounds__(256) void fc_bn3_kernel(
    const float* __restrict__ Draw, const double* __restrict__ p2,
    const float* __restrict__ g2, const float* __restrict__ b2,
    const float* __restrict__ wfc,
    const float* __restrict__ g3, const float* __restrict__ b3,
    float* __restrict__ E, unsigned int* __restrict__ counter,
    float* __restrict__ out)
{
    int tid = threadIdx.x;

    __shared__ float sc2s[10], sh2s[10];
    if (tid < 10) {
        const double N2 = 64.0 * 118.0 * 2.0;
        double s = 0.0, q = 0.0;
        for (int bb = 0; bb < 64; bb++) {
            s += p2[tid * 64 + bb];
            q += p2[640 + tid * 64 + bb];
        }
        double m = s / N2;
        double v = q / N2 - m * m;
        float sc = g2[tid] * rsqrtf((float)v + BN_EPS);
        sc2s[tid] = sc;
        sh2s[tid] = b2[tid] - (float)m * sc;
    }
    __syncthreads();

    int pair = blockIdx.x * 4 + (tid >> 6);
    int lane = tid & 63;
    int b = pair / 10, co = pair % 10;
    const float* dp = Draw + (size_t)b * 590;
    const float* wp = wfc + (size_t)co * 590;
    float s = 0.f;
    #pragma unroll
    for (int j = 0; j < 10; j++) {
        int k = lane + j * 64;
        if (k < 590) {
            int c = k / 59;
            float x = fmaxf(0.f, dp[k] * sc2s[c] + sh2s[c]);
            s += fabsf(x - wp[k]);
        }
    }
    #pragma unroll
    for (int ofs = 32; ofs > 0; ofs >>= 1) s += __shfl_down(s, ofs, 64);
    if (lane == 0) atomicExch(&E[pair], -s);   // device-scope publish

    // ---- last-block BN3 ----
    __shared__ unsigned int lastflag;
    __syncthreads();                            // all 4 waves' E published
    if (tid == 0) {
        __threadfence();
        lastflag = (atomicAdd(counter, 1u) == 159u) ? 1u : 0u;
    }
    __syncthreads();
    if (lastflag) {
        __threadfence();                        // acquire before reading E
        __shared__ float E_lds[640];
        __shared__ float sc3s[10], sh3s[10];
        for (int i = tid; i < 640; i += 256) E_lds[i] = E[i];
        __syncthreads();
        if (tid < 10) {
            double sm = 0.0, ss = 0.0;
            for (int bb = 0; bb < 64; bb++) {
                double v = (double)E_lds[bb * 10 + tid];
                sm += v; ss += v * v;
            }
            double m = sm / 64.0;
            double v = ss / 64.0 - m * m;
            float sc = g3[tid] * rsqrtf((float)v + BN_EPS);
            sc3s[tid] = sc;
            sh3s[tid] = b3[tid] - (float)m * sc;
        }
        __syncthreads();
        for (int i = tid; i < 640; i += 256) {
            int c = i % 10;
            out[i] = E_lds[i] * sc3s[c] + sh3s[c];
        }
    }
}

extern "C" void kernel_launch(void* const* d_in, const int* in_sizes, int n_in,
                              void* d_out, int out_size, void* d_ws, size_t ws_size,
                              hipStream_t stream) {
    const float* in  = (const float*)d_in[0];
    const float* w1  = (const float*)d_in[1];
    const float* g1  = (const float*)d_in[2];
    const float* b1  = (const float*)d_in[3];
    const float* w2  = (const float*)d_in[4];
    const float* g2  = (const float*)d_in[5];
    const float* b2  = (const float*)d_in[6];
    const float* wfc = (const float*)d_in[7];
    const float* g3  = (const float*)d_in[8];
    const float* b3  = (const float*)d_in[9];
    float* out = (float*)d_out;

    double* p1 = (double*)d_ws;                  // [2][5][128]  = 1280 doubles
    double* p2 = p1 + 1280;                      // [2][10][64]  = 1280 doubles
    float* Bv   = (float*)((char*)d_ws + 20480); // raw pooled1, 78080 floats
    float* Draw = Bv + 78080;                    // raw pooled2, 37760 floats
    float* Ev   = Draw + 37760;                  // fc out, 640 floats
    unsigned int* counter = (unsigned int*)(Ev + 640);

    conv1p1_kernel<<<640, 256, 0, stream>>>(in, w1, Bv, p1, counter);
    conv2p2_kernel<<<640, 64, 0, stream>>>(Bv, p1, p2, g1, b1, w2, Draw);
    fc_bn3_kernel<<<160, 256, 0, stream>>>(Draw, p2, g2, b2, wfc, g3, b3,
                                           Ev, counter, out);
}